// Round 12
// baseline (487.104 us; speedup 1.0000x reference)
//
#include <hip/hip_runtime.h>
#include <float.h>

// VectorQuantizer: N=262144 rows of D=64 fp32, K=1024 codebook rows.
// out = [x_quantized (N*D f32) | embed_inds (N, written as f32)]
//
// Bit-exact np-fp32 semantics (verified R4): score = fmaf(-2, seq-dot,
// fadd(xnorm, enorm)); pairwise-8 norms; strict < ascending k (first-min).
//
// R12: GEMM-style register tiling. Each thread owns an 8x8 ACCUMULATOR tile
// (computed values -> cannot be rematerialized; R9-R11 showed the allocator
// reloads any cached LOADED value to chase occupancy). Both operands stream
// from LDS: x-tile [128 rows] staged once, cb-tile [128 rows] per k-tile.
// 16 FMA per LDS b128 read; stride-68 rows + strided row assignment makes
// every read broadcast or 2-way (free).

static constexpr int D_DIM = 64;
static constexpr int K_CB  = 1024;
static constexpr int TPB   = 256;          // 4 waves; thread = (ty,tx) 16x16
static constexpr int BM    = 128;          // x rows per block
static constexpr int BN    = 128;          // cb rows per k-tile
static constexpr int NKT   = K_CB / BN;    // 8
static constexpr int XS    = 68;           // padded LDS row stride (floats)

// numpy pairwise-8 sum of squares of 64 values held as 16 float4s.
#define NP_INIT(c0, c1)                                                     \
    float ax = __fmul_rn(c0.x, c0.x), ay = __fmul_rn(c0.y, c0.y),           \
          az = __fmul_rn(c0.z, c0.z), aw = __fmul_rn(c0.w, c0.w);           \
    float bx = __fmul_rn(c1.x, c1.x), by = __fmul_rn(c1.y, c1.y),           \
          bz = __fmul_rn(c1.z, c1.z), bw = __fmul_rn(c1.w, c1.w);
#define NP_ACC(ce, co)                                                      \
    ax = __fadd_rn(ax, __fmul_rn(ce.x, ce.x));                              \
    ay = __fadd_rn(ay, __fmul_rn(ce.y, ce.y));                              \
    az = __fadd_rn(az, __fmul_rn(ce.z, ce.z));                              \
    aw = __fadd_rn(aw, __fmul_rn(ce.w, ce.w));                              \
    bx = __fadd_rn(bx, __fmul_rn(co.x, co.x));                              \
    by = __fadd_rn(by, __fmul_rn(co.y, co.y));                              \
    bz = __fadd_rn(bz, __fmul_rn(co.z, co.z));                              \
    bw = __fadd_rn(bw, __fmul_rn(co.w, co.w));
#define NP_TREE()                                                           \
    __fadd_rn(__fadd_rn(__fadd_rn(ax, ay), __fadd_rn(az, aw)),              \
              __fadd_rn(__fadd_rn(bx, by), __fadd_rn(bz, bw)))

__device__ __forceinline__ float np_pair_sq16(
        float4 c0, float4 c1, float4 c2, float4 c3,
        float4 c4, float4 c5, float4 c6, float4 c7,
        float4 c8, float4 c9, float4 c10, float4 c11,
        float4 c12, float4 c13, float4 c14, float4 c15) {
    NP_INIT(c0, c1)
    NP_ACC(c2, c3)  NP_ACC(c4, c5)  NP_ACC(c6, c7)
    NP_ACC(c8, c9)  NP_ACC(c10, c11) NP_ACC(c12, c13) NP_ACC(c14, c15)
    return NP_TREE();
}

__global__ void __launch_bounds__(TPB)
__attribute__((amdgpu_waves_per_eu(2, 2)))
vq_kernel(
        const float* __restrict__ x, const float* __restrict__ cb,
        float* __restrict__ out_q, float* __restrict__ out_idx) {
    __shared__ float xs[BM * XS];    // 34816 B  x tile (stride-68)
    __shared__ float cs[BN * XS];    // 34816 B  cb tile (stride-68)
    __shared__ float es[K_CB];       // 4096 B   e-norms
    __shared__ float xn_s[BM];       // 512 B
    __shared__ int   bks[BM];        // 512 B    (~74.8 KB total -> 2 blocks/CU)

    const int tid = threadIdx.x;
    const int tx  = tid & 15;        // cb-dim thread coord
    const int ty  = tid >> 4;        // x-dim thread coord
    const size_t row0 = (size_t)blockIdx.x * BM;
    const float4* cb4 = reinterpret_cast<const float4*>(cb);

    // ---- phase A: all 1024 e-norms (numpy pairwise order), 4 per thread ----
#pragma unroll
    for (int j = 0; j < K_CB / TPB; ++j) {
        const int k = tid + TPB * j;
        const float4* cr = cb4 + (size_t)k * 16;
        float4 c0 = cr[0],  c1 = cr[1],  c2 = cr[2],  c3 = cr[3],
               c4 = cr[4],  c5 = cr[5],  c6 = cr[6],  c7 = cr[7],
               c8 = cr[8],  c9 = cr[9],  c10 = cr[10], c11 = cr[11],
               c12 = cr[12], c13 = cr[13], c14 = cr[14], c15 = cr[15];
        es[k] = np_pair_sq16(c0, c1, c2, c3, c4, c5, c6, c7,
                             c8, c9, c10, c11, c12, c13, c14, c15);
    }

    // ---- phase B: stage x tile (coalesced read, stride-68 LDS write) ----
    {
        const float4* g = reinterpret_cast<const float4*>(x + row0 * D_DIM);
#pragma unroll
        for (int j = 0; j < BM * 16 / TPB; ++j) {     // 8
            const int f = tid + TPB * j;
            const int r = f >> 4, c = f & 15;
            *reinterpret_cast<float4*>(&xs[r * XS + c * 4]) = g[f];
        }
    }
    __syncthreads();

    // ---- phase B2: x-norms from the LDS tile ----
    if (tid < BM) {
        const float* rp = &xs[tid * XS];
        float4 c0 = *(const float4*)&rp[0],  c1 = *(const float4*)&rp[4],
               c2 = *(const float4*)&rp[8],  c3 = *(const float4*)&rp[12],
               c4 = *(const float4*)&rp[16], c5 = *(const float4*)&rp[20],
               c6 = *(const float4*)&rp[24], c7 = *(const float4*)&rp[28],
               c8 = *(const float4*)&rp[32], c9 = *(const float4*)&rp[36],
               c10 = *(const float4*)&rp[40], c11 = *(const float4*)&rp[44],
               c12 = *(const float4*)&rp[48], c13 = *(const float4*)&rp[52],
               c14 = *(const float4*)&rp[56], c15 = *(const float4*)&rp[60];
        xn_s[tid] = np_pair_sq16(c0, c1, c2, c3, c4, c5, c6, c7,
                                 c8, c9, c10, c11, c12, c13, c14, c15);
    }
    __syncthreads();

    // My 8 rows are ty + 16*i (strided -> conflict-free LDS reads).
    float xn[8];
#pragma unroll
    for (int i = 0; i < 8; ++i) xn[i] = xn_s[ty + 16 * i];

    float best[8]; int bestk[8];
#pragma unroll
    for (int i = 0; i < 8; ++i) { best[i] = FLT_MAX; bestk[i] = 0; }

    for (int t = 0; t < NKT; ++t) {
        __syncthreads();               // protect cs from previous readers
        {                              // stage cb tile t
            const float4* g = cb4 + (size_t)t * BN * 16;
#pragma unroll
            for (int j = 0; j < BN * 16 / TPB; ++j) {
                const int f = tid + TPB * j;
                const int r = f >> 4, c = f & 15;
                *reinterpret_cast<float4*>(&cs[r * XS + c * 4]) = g[f];
            }
        }
        __syncthreads();

        float acc[8][8];
#pragma unroll
        for (int i = 0; i < 8; ++i)
#pragma unroll
            for (int j = 0; j < 8; ++j) acc[i][j] = 0.f;

#pragma unroll 2
        for (int dc = 0; dc < 16; ++dc) {
            float4 cq[8];
#pragma unroll
            for (int j = 0; j < 8; ++j)
                cq[j] = *(const float4*)&cs[(tx + 16 * j) * XS + dc * 4];
            float4 xq[4];
#pragma unroll
            for (int i = 0; i < 4; ++i)
                xq[i] = *(const float4*)&xs[(ty + 16 * i) * XS + dc * 4];
#pragma unroll
            for (int i = 0; i < 4; ++i)
#pragma unroll
                for (int j = 0; j < 8; ++j) {
                    acc[i][j] = __fmaf_rn(xq[i].x, cq[j].x, acc[i][j]);
                    acc[i][j] = __fmaf_rn(xq[i].y, cq[j].y, acc[i][j]);
                    acc[i][j] = __fmaf_rn(xq[i].z, cq[j].z, acc[i][j]);
                    acc[i][j] = __fmaf_rn(xq[i].w, cq[j].w, acc[i][j]);
                }
#pragma unroll
            for (int i = 0; i < 4; ++i)
                xq[i] = *(const float4*)&xs[(ty + 16 * (i + 4)) * XS + dc * 4];
#pragma unroll
            for (int i = 0; i < 4; ++i)
#pragma unroll
                for (int j = 0; j < 8; ++j) {
                    acc[i + 4][j] = __fmaf_rn(xq[i].x, cq[j].x, acc[i + 4][j]);
                    acc[i + 4][j] = __fmaf_rn(xq[i].y, cq[j].y, acc[i + 4][j]);
                    acc[i + 4][j] = __fmaf_rn(xq[i].z, cq[j].z, acc[i + 4][j]);
                    acc[i + 4][j] = __fmaf_rn(xq[i].w, cq[j].w, acc[i + 4][j]);
                }
        }

        // epilogue: scores + running first-min (k ascending: t, then j)
#pragma unroll
        for (int j = 0; j < 8; ++j) {
            const int k = t * BN + tx + 16 * j;
            const float en = es[k];
#pragma unroll
            for (int i = 0; i < 8; ++i) {
                const float s = __fmaf_rn(-2.f, acc[i][j], __fadd_rn(xn[i], en));
                if (s < best[i]) { best[i] = s; bestk[i] = k; }
            }
        }
    }

    // ---- cross-lane reduce over the 16 tx-lanes; exact first-min ----
#pragma unroll
    for (int i = 0; i < 8; ++i) {
        float b = best[i]; int bk = bestk[i];
#pragma unroll
        for (int m = 1; m < 16; m <<= 1) {
            const float b2 = __shfl_xor(b, m);
            const int   k2 = __shfl_xor(bk, m);
            if (b2 < b || (b2 == b && k2 < bk)) { b = b2; bk = k2; }
        }
        if (tx == 0) {
            const int r = ty + 16 * i;
            bks[r] = bk;
            out_idx[row0 + r] = (float)bk;
        }
    }
    __syncthreads();

    // ---- coalesced gather-write of x_quantized ----
    float4* oq = reinterpret_cast<float4*>(out_q + row0 * D_DIM);
#pragma unroll
    for (int j = 0; j < BM * 16 / TPB; ++j) {
        const int f = tid + TPB * j;
        const int r = f >> 4, c = f & 15;
        oq[f] = cb4[(size_t)bks[r] * 16 + c];
    }
}

extern "C" void kernel_launch(void* const* d_in, const int* in_sizes, int n_in,
                              void* d_out, int out_size, void* d_ws, size_t ws_size,
                              hipStream_t stream) {
    const float* x  = (const float*)d_in[0];
    const float* cb = (const float*)d_in[1];
    const int n_rows = in_sizes[0] / D_DIM;     // 262144

    float* out_q   = (float*)d_out;
    float* out_idx = out_q + (size_t)n_rows * D_DIM;

    vq_kernel<<<n_rows / BM, TPB, 0, stream>>>(x, cb, out_q, out_idx);
}